// Round 15
// baseline (213.603 us; speedup 1.0000x reference)
//
#include <hip/hip_runtime.h>
#include <hip/hip_fp16.h>
#include <math.h>

#define NPROJ 96
#define NANG  96
#define DET   192
#define NPIX  16384            // 128*128
#define SLICE (NANG*DET)       // 18432

// DSD/DU = DSD/DV = 1000/3.5
#define KPROJ 285.7142857142857f

__device__ __forceinline__ float frcp(float x) { return __builtin_amdgcn_rcpf(x); }

__device__ __forceinline__ float ffract(float x) {
#if __has_builtin(__builtin_amdgcn_fractf)
    return __builtin_amdgcn_fractf(x);
#else
    return x - floorf(x);
#endif
}

typedef __fp16 h2 __attribute__((ext_vector_type(2)));

__device__ __forceinline__ unsigned pack2(float a, float b) {
    h2 p = __builtin_amdgcn_cvt_pkrtz(a, b);
    return __builtin_bit_cast(unsigned, p);
}
__device__ __forceinline__ h2 as_h2(unsigned u) { return __builtin_bit_cast(h2, u); }

#if __has_builtin(__builtin_amdgcn_fdot2)
#define FDOT2(a, b, c) __builtin_amdgcn_fdot2((a), (b), (c), false)
#else
__device__ __forceinline__ float FDOT2(h2 a, h2 b, float c) {
    return c + (float)a[0] * (float)b[0] + (float)a[1] * (float)b[1];
}
#endif

// ---------------------------------------------------------------------------
// K1: deriv = grad_lastdim(sino * weight) -> DIFFERENCE pairs:
// derivp[row][d] = half2(g[d], g[d+1]-g[d])  =>  lerp weight is (1, f).
// ---------------------------------------------------------------------------
__global__ __launch_bounds__(192) void k_deriv(const float* __restrict__ sino,
                                               const float* __restrict__ wgt,
                                               unsigned* __restrict__ derivp) {
    __shared__ float row[DET];
    const int r = blockIdx.x;          // p*96 + a
    const int d = threadIdx.x;         // 0..191
    const int base = r * DET + d;
    row[d] = sino[base] * wgt[base];
    __syncthreads();
    auto grad = [&](int i) -> float {
        i = (i > DET-1) ? DET-1 : i;
        if (i == 0)       return row[1] - row[0];
        if (i == DET-1)   return row[DET-1] - row[DET-2];
        return 0.5f * (row[i+1] - row[i-1]);
    };
    const float g0 = grad(d), g1 = grad(d+1);
    derivp[base] = pack2(g0, g1 - g0);
}

// ---------------------------------------------------------------------------
// K2: 2D backprojection + cosine weighting (r13 proven loop, diff-pairs):
// per sample: pos fma+fma-share, cvt, fract, pkrtz(1,f), dword gather, fdot2.
// Epilogue writes the every-v QUAD layout in DIFFERENCE form:
//   wq[p][v][u] = uint4 of dpr(v..v+3,u),
//   dpr(v,u) = half2( w[v][u], w[v][u+1]-w[v][u] ).
// grid (96 p, 32 chunks), block 256, 2 px/thread. No masks.
// ---------------------------------------------------------------------------
__global__ __launch_bounds__(256) void k_bp2d(const unsigned* __restrict__ derivp,
                                              unsigned* __restrict__ wq_dw) {
    __shared__ float sc[NANG], ss[NANG];
    __shared__ float buf[512];
    const int p   = blockIdx.x;
    const int tid = threadIdx.x;

    if (tid < NANG) {
        float s_, c_;
        sincosf((float)tid * (float)(3.14159265358979323846 / 96.0), &s_, &c_);
        sc[tid] = c_; ss[tid] = s_;
    }

    const int pixbase = blockIdx.y * 512;
    const int px0 = pixbase + 2*tid;       // even x
    const float fx0 = (float)(px0 & 127) - 63.5f;
    const float fy  = (float)(px0 >> 7)  - 63.5f;
    float acc0 = 0.0f, acc1 = 0.0f;
    __syncthreads();   // trig ready

    const unsigned* rowp = derivp + p * SLICE;
    for (int a = 0; a < NANG; ++a, rowp += DET) {
        const float cb = sc[a], sb = ss[a];
        const float pos0 = fmaf(cb, fx0, fmaf(sb, fy, 95.5f));
        const float pos1 = pos0 + cb;
        const int i0 = (int)pos0;
        const int i1 = (int)pos1;
        const float f0 = ffract(pos0);
        const float f1 = ffract(pos1);
        acc0 = FDOT2(as_h2(rowp[i0]), as_h2(pack2(1.0f, f0)), acc0);
        acc1 = FDOT2(as_h2(rowp[i1]), as_h2(pack2(1.0f, f1)), acc1);
    }

    const float fx1 = fx0 + 1.0f;
    buf[2*tid]     = acc0 * (1000.0f * rsqrtf(1000000.0f + fx0*fx0 + fy*fy));
    buf[2*tid + 1] = acc1 * (1000.0f * rsqrtf(1000000.0f + fx1*fx1 + fy*fy));
    __syncthreads();

    // epilogue: difference-pair of row v lands in slot k of quad v-k, k=0..3
    unsigned* sq = wq_dw + p * (NPIX * 4);
    #pragma unroll
    for (int i = 0; i < 2; ++i) {
        const int l   = 2*tid + i;
        const int pix = pixbase + l;
        const int u   = pix & 127;
        const int v   = pix >> 7;
        const float v0 = buf[l];
        const float v1 = (u < 127) ? buf[l + 1] : 0.0f;   // u=127 pair unused
        const unsigned pr = pack2(v0, v1 - v0);
        #pragma unroll
        for (int k = 0; k < 4; ++k) {
            const int vb = v - k;
            if (vb >= 0) sq[(((vb << 7) + u) << 2) + k] = pr;
        }
    }
}

// ---------------------------------------------------------------------------
// K3: 3D cone-beam backprojection + PReLU — r13 winner + diff-pair weights:
// every-v quad loads, ONE dwordx4 per z-pair; u-weights (w2, fu*w2) — the
// (1-fu) sub and one mul are gone. z=B slot select: 1 sub + 2 cndmask.
// grid (64 y-pairs, 32 z-chunks) = 2048 blocks = 32 waves/CU.
// pu in [11,116], pv in [19,108] -> no masks.
// ---------------------------------------------------------------------------
__global__ __launch_bounds__(256) void k_bp3d_q(const uint4* __restrict__ wq,
                                                const float* __restrict__ prelu,
                                                float* __restrict__ out) {
    __shared__ float sc[NPROJ], ss[NPROJ];
    const int tid = threadIdx.x;
    const int x   = tid & 127;
    const int y   = (blockIdx.x << 1) | (tid >> 7);
    const int z0  = blockIdx.y << 2;

    if (tid < NPROJ) {
        float s_, c_;
        sincosf((float)tid * (float)(2.0 * 3.14159265358979323846 / 96.0), &s_, &c_);
        sc[tid] = c_; ss[tid] = s_;
    }

    const float fx  = (float)x - 63.5f;
    const float fy  = (float)y - 63.5f;
    const float zlo = (float)z0 - 63.5f;

    float acc[4];
    #pragma unroll
    for (int j = 0; j < 4; ++j) acc[j] = 0.0f;

    __syncthreads();   // trig ready — the only barrier

    const uint4* bb = wq;                // per-beta slice = 128*128 uint4
    for (int b = 0; b < NPROJ; ++b, bb += NPIX) {
        const float cb    = sc[b], sb = ss[b];
        const float t     = fmaf(fx, cb,  fy * sb);
        const float sdist = fmaf(fy, cb, -fx * sb);
        const float invr  = frcp(500.0f + t);
        const float pu    = fmaf(KPROJ * sdist, invr, 63.5f);
        const int   iu0   = (int)pu;             // pu in [11, 116]
        const float fu    = ffract(pu);
        float w2 = 1000.0f * invr; w2 *= w2;
        const float Kz    = KPROJ * invr;
        const h2    wuw   = as_h2(pack2(w2, fu * w2));   // diff-pair weights

        #pragma unroll
        for (int pr2 = 0; pr2 < 2; ++pr2) {      // z-pairs (0,1), (2,3)
            const float pvA = fmaf(Kz, zlo + (float)(2*pr2), 63.5f);
            const float pvB = pvA + Kz;
            const int   ivA = (int)pvA;          // pv in [19, 108]
            const int   ivB = (int)pvB;          // ivA or ivA+1
            const float fvA = ffract(pvA);
            const float fvB = ffract(pvB);
            const uint4 q   = bb[(ivA << 7) + iu0];   // rows ivA..ivA+3
            const int   d   = ivB - ivA;              // 0 or 1
            const float tA  = FDOT2(as_h2(q.x), wuw, 0.0f);
            const float bA  = FDOT2(as_h2(q.y), wuw, 0.0f);
            acc[2*pr2]     += fmaf(fvA, bA - tA, tA);
            const unsigned tBv = d ? q.y : q.x;
            const unsigned bBv = d ? q.z : q.y;
            const float tB  = FDOT2(as_h2(tBv), wuw, 0.0f);
            const float bB  = FDOT2(as_h2(bBv), wuw, 0.0f);
            acc[2*pr2 + 1] += fmaf(fvB, bB - tB, tB);
        }
    }

    const float a = prelu[0];
    #pragma unroll
    for (int j = 0; j < 4; ++j) {
        const float v = acc[j];
        out[((z0 + j) << 14) + (y << 7) + x] = (v >= 0.0f) ? v : a * v;
    }
}

// ---------------------------------------------------------------------------
extern "C" void kernel_launch(void* const* d_in, const int* in_sizes, int n_in,
                              void* d_out, int out_size, void* d_ws, size_t ws_size,
                              hipStream_t stream) {
    const float* sino  = (const float*)d_in[0];   // (1,1,96,96,192)
    const float* wgt   = (const float*)d_in[1];   // (1,96,96,192)
    const float* prelu = (const float*)d_in[2];   // (1,)
    float* out = (float*)d_out;                   // 128^3 floats

    unsigned* wq_dw  = (unsigned*)d_ws;                        // 25.17 MB quads
    unsigned* derivp = wq_dw + (size_t)NPROJ * NPIX * 4;       // 7.08 MB pairs

    k_deriv<<<dim3(NPROJ * NANG), dim3(192), 0, stream>>>(sino, wgt, derivp);
    k_bp2d <<<dim3(NPROJ, 32),    dim3(256), 0, stream>>>(derivp, wq_dw);
    k_bp3d_q<<<dim3(64, 32),      dim3(256), 0, stream>>>((const uint4*)wq_dw, prelu, out);
}

// Round 16
// 189.045 us; speedup vs baseline: 1.1299x; 1.1299x over previous
//
#include <hip/hip_runtime.h>
#include <hip/hip_fp16.h>
#include <math.h>

#define NPROJ 96
#define NANG  96
#define DET   192
#define NPIX  16384            // 128*128
#define SLICE (NANG*DET)       // 18432

// DSD/DU = DSD/DV = 1000/3.5
#define KPROJ 285.7142857142857f

__device__ __forceinline__ float frcp(float x) { return __builtin_amdgcn_rcpf(x); }

__device__ __forceinline__ float ffract(float x) {
#if __has_builtin(__builtin_amdgcn_fractf)
    return __builtin_amdgcn_fractf(x);
#else
    return x - floorf(x);
#endif
}

typedef __fp16 h2 __attribute__((ext_vector_type(2)));

__device__ __forceinline__ unsigned pack2(float a, float b) {
    h2 p = __builtin_amdgcn_cvt_pkrtz(a, b);
    return __builtin_bit_cast(unsigned, p);
}
__device__ __forceinline__ h2 as_h2(unsigned u) { return __builtin_bit_cast(h2, u); }

#if __has_builtin(__builtin_amdgcn_fdot2)
#define FDOT2(a, b, c) __builtin_amdgcn_fdot2((a), (b), (c), false)
#else
__device__ __forceinline__ float FDOT2(h2 a, h2 b, float c) {
    return c + (float)a[0] * (float)b[0] + (float)a[1] * (float)b[1];
}
#endif

// ---------------------------------------------------------------------------
// K1: deriv = grad_lastdim(sino * weight) -> DIFFERENCE pairs:
// derivp[row][d] = half2(g[d], g[d+1]-g[d])  =>  lerp weight is (1, f).
// ---------------------------------------------------------------------------
__global__ __launch_bounds__(192) void k_deriv(const float* __restrict__ sino,
                                               const float* __restrict__ wgt,
                                               unsigned* __restrict__ derivp) {
    __shared__ float row[DET];
    const int r = blockIdx.x;          // p*96 + a
    const int d = threadIdx.x;         // 0..191
    const int base = r * DET + d;
    row[d] = sino[base] * wgt[base];
    __syncthreads();
    auto grad = [&](int i) -> float {
        i = (i > DET-1) ? DET-1 : i;
        if (i == 0)       return row[1] - row[0];
        if (i == DET-1)   return row[DET-1] - row[DET-2];
        return 0.5f * (row[i+1] - row[i-1]);
    };
    const float g0 = grad(d), g1 = grad(d+1);
    derivp[base] = pack2(g0, g1 - g0);
}

// ---------------------------------------------------------------------------
// K2: 2D backprojection + cosine weighting — r13 WINNER structure:
// 2 px/thread at STRIDE 256 (lane-adjacent threads = consecutive pixels ->
// minimal wave gather span; r14/r15's 2*tid pair mapping cost 10-20 us).
// Diff-pair weights (1, f): no (1-f) sub. 1 dword gather per px-angle.
// Epilogue writes every-v QUAD layout in DIFFERENCE form:
//   wq[p][v][u] = uint4 of dpr(v..v+3,u), dpr = (w[v][u], w[v][u+1]-w[v][u]).
// grid (96 p, 32 chunks), block 256. No masks.
// ---------------------------------------------------------------------------
__global__ __launch_bounds__(256) void k_bp2d(const unsigned* __restrict__ derivp,
                                              unsigned* __restrict__ wq_dw) {
    __shared__ float sc[NANG], ss[NANG];
    __shared__ float buf[512];
    const int p   = blockIdx.x;
    const int tid = threadIdx.x;

    if (tid < NANG) {
        float s_, c_;
        sincosf((float)tid * (float)(3.14159265358979323846 / 96.0), &s_, &c_);
        sc[tid] = c_; ss[tid] = s_;
    }

    const int pixbase = blockIdx.y * 512;
    float acc[2], fx[2], fy[2];
    #pragma unroll
    for (int i = 0; i < 2; ++i) {
        const int pix = pixbase + i*256 + tid;
        fx[i] = (float)(pix & 127) - 63.5f;
        fy[i] = (float)(pix >> 7)  - 63.5f;
        acc[i] = 0.0f;
    }
    __syncthreads();   // trig ready

    const unsigned* rowp = derivp + p * SLICE;   // advances by DET per angle
    for (int a = 0; a < NANG; ++a, rowp += DET) {
        const float cb = sc[a], sb = ss[a];
        #pragma unroll
        for (int i = 0; i < 2; ++i) {
            const float pos = fmaf(cb, fx[i], fmaf(sb, fy[i], 95.5f));
            const int   i0  = (int)pos;            // pos > 0 always
            const float f   = ffract(pos);
            acc[i] = FDOT2(as_h2(rowp[i0]), as_h2(pack2(1.0f, f)), acc[i]);
        }
    }

    #pragma unroll
    for (int i = 0; i < 2; ++i) {
        const float w = 1000.0f * rsqrtf(1000000.0f + fx[i]*fx[i] + fy[i]*fy[i]);
        buf[i*256 + tid] = acc[i] * w;
    }
    __syncthreads();

    // epilogue: difference-pair of row v lands in slot k of quad v-k, k=0..3
    unsigned* sq = wq_dw + p * (NPIX * 4);
    #pragma unroll
    for (int i = 0; i < 2; ++i) {
        const int l   = i*256 + tid;
        const int pix = pixbase + l;
        const int u   = pix & 127;
        const int v   = pix >> 7;
        const float v0 = buf[l];
        const float v1 = (u < 127) ? buf[l + 1] : 0.0f;   // u=127 pair unused
        const unsigned pr = pack2(v0, v1 - v0);
        #pragma unroll
        for (int k = 0; k < 4; ++k) {
            const int vb = v - k;
            if (vb >= 0) sq[(((vb << 7) + u) << 2) + k] = pr;
        }
    }
}

// ---------------------------------------------------------------------------
// K3: 3D cone-beam backprojection + PReLU — r13/r15 winner (flat across
// both): every-v quad loads, ONE dwordx4 per z-pair; diff-pair u-weights
// (w2, fu*w2). grid (64 y-pairs, 32 z-chunks) = 2048 blocks = 32 waves/CU.
// pu in [11,116], pv in [19,108] -> no masks.
// ---------------------------------------------------------------------------
__global__ __launch_bounds__(256) void k_bp3d_q(const uint4* __restrict__ wq,
                                                const float* __restrict__ prelu,
                                                float* __restrict__ out) {
    __shared__ float sc[NPROJ], ss[NPROJ];
    const int tid = threadIdx.x;
    const int x   = tid & 127;
    const int y   = (blockIdx.x << 1) | (tid >> 7);
    const int z0  = blockIdx.y << 2;

    if (tid < NPROJ) {
        float s_, c_;
        sincosf((float)tid * (float)(2.0 * 3.14159265358979323846 / 96.0), &s_, &c_);
        sc[tid] = c_; ss[tid] = s_;
    }

    const float fx  = (float)x - 63.5f;
    const float fy  = (float)y - 63.5f;
    const float zlo = (float)z0 - 63.5f;

    float acc[4];
    #pragma unroll
    for (int j = 0; j < 4; ++j) acc[j] = 0.0f;

    __syncthreads();   // trig ready — the only barrier

    const uint4* bb = wq;                // per-beta slice = 128*128 uint4
    for (int b = 0; b < NPROJ; ++b, bb += NPIX) {
        const float cb    = sc[b], sb = ss[b];
        const float t     = fmaf(fx, cb,  fy * sb);
        const float sdist = fmaf(fy, cb, -fx * sb);
        const float invr  = frcp(500.0f + t);
        const float pu    = fmaf(KPROJ * sdist, invr, 63.5f);
        const int   iu0   = (int)pu;             // pu in [11, 116]
        const float fu    = ffract(pu);
        float w2 = 1000.0f * invr; w2 *= w2;
        const float Kz    = KPROJ * invr;
        const h2    wuw   = as_h2(pack2(w2, fu * w2));   // diff-pair weights

        #pragma unroll
        for (int pr2 = 0; pr2 < 2; ++pr2) {      // z-pairs (0,1), (2,3)
            const float pvA = fmaf(Kz, zlo + (float)(2*pr2), 63.5f);
            const float pvB = pvA + Kz;
            const int   ivA = (int)pvA;          // pv in [19, 108]
            const int   ivB = (int)pvB;          // ivA or ivA+1
            const float fvA = ffract(pvA);
            const float fvB = ffract(pvB);
            const uint4 q   = bb[(ivA << 7) + iu0];   // rows ivA..ivA+3
            const int   d   = ivB - ivA;              // 0 or 1
            const float tA  = FDOT2(as_h2(q.x), wuw, 0.0f);
            const float bA  = FDOT2(as_h2(q.y), wuw, 0.0f);
            acc[2*pr2]     += fmaf(fvA, bA - tA, tA);
            const unsigned tBv = d ? q.y : q.x;
            const unsigned bBv = d ? q.z : q.y;
            const float tB  = FDOT2(as_h2(tBv), wuw, 0.0f);
            const float bB  = FDOT2(as_h2(bBv), wuw, 0.0f);
            acc[2*pr2 + 1] += fmaf(fvB, bB - tB, tB);
        }
    }

    const float a = prelu[0];
    #pragma unroll
    for (int j = 0; j < 4; ++j) {
        const float v = acc[j];
        out[((z0 + j) << 14) + (y << 7) + x] = (v >= 0.0f) ? v : a * v;
    }
}

// ---------------------------------------------------------------------------
extern "C" void kernel_launch(void* const* d_in, const int* in_sizes, int n_in,
                              void* d_out, int out_size, void* d_ws, size_t ws_size,
                              hipStream_t stream) {
    const float* sino  = (const float*)d_in[0];   // (1,1,96,96,192)
    const float* wgt   = (const float*)d_in[1];   // (1,96,96,192)
    const float* prelu = (const float*)d_in[2];   // (1,)
    float* out = (float*)d_out;                   // 128^3 floats

    unsigned* wq_dw  = (unsigned*)d_ws;                        // 25.17 MB quads
    unsigned* derivp = wq_dw + (size_t)NPROJ * NPIX * 4;       // 7.08 MB pairs

    k_deriv<<<dim3(NPROJ * NANG), dim3(192), 0, stream>>>(sino, wgt, derivp);
    k_bp2d <<<dim3(NPROJ, 32),    dim3(256), 0, stream>>>(derivp, wq_dw);
    k_bp3d_q<<<dim3(64, 32),      dim3(256), 0, stream>>>((const uint4*)wq_dw, prelu, out);
}